// Round 2
// baseline (94.513 us; speedup 1.0000x reference)
//
#include <hip/hip_runtime.h>

// SparseMatmul3D: out[b,n,m] = sum_k x[b,n,k] * y[b,m,k]
// B=4, N=M=4096, D=64, fp32 in/out. Write-bound (268 MB out, floor ~38us).
// R1: stores were 16x64B half-line segments per wave instr -> ~3 TB/s.
// R2: stage C-tile in LDS (XOR-swizzled), store fill-style full 128B lines.

#define BATCH 4
#define NN 4096
#define MM 4096
#define DD 64

typedef __attribute__((ext_vector_type(8))) short bf16x8;
typedef __attribute__((ext_vector_type(4))) float f32x4;

__device__ __forceinline__ unsigned short f2bf(float f) {
    unsigned u = __builtin_bit_cast(unsigned, f);
    u += 0x7FFFu + ((u >> 16) & 1u);   // round-to-nearest-even
    return (unsigned short)(u >> 16);
}

__device__ __forceinline__ bf16x8 load8_bf16(const float* __restrict__ p) {
    f32x4 v0 = *reinterpret_cast<const f32x4*>(p);
    f32x4 v1 = *reinterpret_cast<const f32x4*>(p + 4);
    bf16x8 r;
    r[0] = (short)f2bf(v0[0]); r[1] = (short)f2bf(v0[1]);
    r[2] = (short)f2bf(v0[2]); r[3] = (short)f2bf(v0[3]);
    r[4] = (short)f2bf(v1[0]); r[5] = (short)f2bf(v1[1]);
    r[6] = (short)f2bf(v1[2]); r[7] = (short)f2bf(v1[3]);
    return r;
}

__global__ __launch_bounds__(256) void
SparseMatmul3D_36155034698289_kernel(const float* __restrict__ x,
                                     const float* __restrict__ y,
                                     float* __restrict__ out) {
    const int b    = blockIdx.z;
    const int m0   = blockIdx.x * 128;   // m tile base
    const int n0   = blockIdx.y * 128;   // n tile base
    const int tid  = threadIdx.x;
    const int lane = tid & 63;
    const int w    = tid >> 6;           // wave 0..3: owns n rows [w*32, w*32+32)

    const int row16 = lane & 15;
    const int kgrp  = lane >> 4;         // 0..3 -> k chunk of 8

    const float* __restrict__ xb = x + (size_t)b * NN * DD;
    const float* __restrict__ yb = y + (size_t)b * MM * DD;

    __shared__ float lds[64 * 128];      // 32 KB staging for epilogue

    // B operand = x rows (n side): 2 n-subtiles per wave
    bf16x8 bfrag[2][2];
#pragma unroll
    for (int nt = 0; nt < 2; ++nt) {
        const float* p = xb + (size_t)(n0 + w * 32 + nt * 16 + row16) * DD + kgrp * 8;
        bfrag[nt][0] = load8_bf16(p);
        bfrag[nt][1] = load8_bf16(p + 32);
    }

    f32x4 acc[2][8];
#pragma unroll
    for (int nt = 0; nt < 2; ++nt)
#pragma unroll
        for (int mt = 0; mt < 8; ++mt)
            acc[nt][mt] = (f32x4){0.f, 0.f, 0.f, 0.f};

    // A operand = y rows (m side): 8 m-subtiles, loaded in 2 halves (VGPR cap)
#pragma unroll
    for (int h = 0; h < 2; ++h) {
        bf16x8 afrag[4][2];
#pragma unroll
        for (int mtl = 0; mtl < 4; ++mtl) {
            const float* p = yb + (size_t)(m0 + h * 64 + mtl * 16 + row16) * DD + kgrp * 8;
            afrag[mtl][0] = load8_bf16(p);
            afrag[mtl][1] = load8_bf16(p + 32);
        }
#pragma unroll
        for (int ks = 0; ks < 2; ++ks)
#pragma unroll
            for (int nt = 0; nt < 2; ++nt)
#pragma unroll
                for (int mtl = 0; mtl < 4; ++mtl)
                    acc[nt][h * 4 + mtl] = __builtin_amdgcn_mfma_f32_16x16x32_bf16(
                        afrag[mtl][ks], bfrag[nt][ks], acc[nt][h * 4 + mtl], 0, 0, 0);
    }

    // Epilogue: 2 phases of 64 rows through LDS, then contiguous stores.
    // D layout: col = lane&15 = n-row16; row = (lane>>4)*4+reg = m-local.
    float* __restrict__ ob = out + (size_t)b * NN * MM;

#pragma unroll
    for (int p = 0; p < 2; ++p) {
        if (p) __syncthreads();          // protect LDS reuse
        {
            const int s   = w * 16 + row16;       // staged row [0,64)
            const int swz = (s & 7) << 2;
#pragma unroll
            for (int mt = 0; mt < 8; ++mt) {
                const int col = (mt * 16 + kgrp * 4) ^ swz;
                *reinterpret_cast<f32x4*>(&lds[s * 128 + col]) = acc[p][mt];
            }
        }
        __syncthreads();
#pragma unroll
        for (int it = 0; it < 8; ++it) {
            const int s   = it * 8 + (tid >> 5);  // staged row
            const int m   = (tid & 31) * 4;
            const int col = m ^ ((s & 7) << 2);
            f32x4 v = *reinterpret_cast<const f32x4*>(&lds[s * 128 + col]);
            const int n = n0 + (s >> 4) * 32 + p * 16 + (s & 15);
            __builtin_nontemporal_store(
                v, reinterpret_cast<f32x4*>(ob + (size_t)n * MM + m0 + m));
        }
    }
}

extern "C" void kernel_launch(void* const* d_in, const int* in_sizes, int n_in,
                              void* d_out, int out_size, void* d_ws, size_t ws_size,
                              hipStream_t stream) {
    const float* x = (const float*)d_in[0];
    const float* y = (const float*)d_in[1];
    float* out = (float*)d_out;

    dim3 grid(MM / 128, NN / 128, BATCH);
    dim3 block(256);
    SparseMatmul3D_36155034698289_kernel<<<grid, block, 0, stream>>>(x, y, out);
}